// Round 1
// baseline (612.589 us; speedup 1.0000x reference)
//
#include <hip/hip_runtime.h>
#include <hip/hip_bf16.h>

typedef __bf16 bf16_t;
typedef __bf16 bf16x8 __attribute__((ext_vector_type(8)));
typedef __bf16 bf16x4 __attribute__((ext_vector_type(4)));
typedef float f32x4 __attribute__((ext_vector_type(4)));

#define SCALE_QK 0.08838834764831845f  // 1/sqrt(128)

__device__ __forceinline__ void gload_lds16(const void* g, void* l) {
  __builtin_amdgcn_global_load_lds(
      (const __attribute__((address_space(1))) void*)g,
      (__attribute__((address_space(3))) void*)l, 16, 0, 0);
}

// ---------------- fp32 -> bf16 convert ----------------
__global__ __launch_bounds__(256) void cvt_f32_bf16(
    const float* __restrict__ src, bf16_t* __restrict__ dst, int n4) {
  int i = blockIdx.x * 256 + threadIdx.x;
  const int stride = gridDim.x * 256;
  for (; i < n4; i += stride) {
    f32x4 v = *reinterpret_cast<const f32x4*>(src + (size_t)i * 4);
    bf16x4 r;
    r[0] = (bf16_t)v[0]; r[1] = (bf16_t)v[1];
    r[2] = (bf16_t)v[2]; r[3] = (bf16_t)v[3];
    *reinterpret_cast<bf16x4*>(dst + (size_t)i * 4) = r;
  }
}

// ---------------- bf16 GEMM:  C[M][N] = A[M][K] * W[N][K]^T ----------------
// 128x128 tile, BK=32, 256 threads (4 waves, 2x2 wave grid, 64x64 per wave)
template <typename OutT>
__global__ __launch_bounds__(256) void gemm_bt(
    const bf16_t* __restrict__ A, const bf16_t* __restrict__ W,
    OutT* __restrict__ C, int M, int N, int K) {
  __shared__ bf16_t As[128 * 32];
  __shared__ bf16_t Ws[128 * 32];
  const int tid = threadIdx.x;
  const int lane = tid & 63;
  const int wid = tid >> 6;
  const int wr = wid >> 1, wc = wid & 1;
  const int l15 = lane & 15, lg = lane >> 4;
  const int r0 = blockIdx.y * 128;
  const int c0 = blockIdx.x * 128;

  f32x4 acc[4][4];
#pragma unroll
  for (int mi = 0; mi < 4; ++mi)
#pragma unroll
    for (int ni = 0; ni < 4; ++ni)
#pragma unroll
      for (int j = 0; j < 4; ++j) acc[mi][ni][j] = 0.f;

  for (int k0 = 0; k0 < K; k0 += 32) {
#pragma unroll
    for (int s = 0; s < 2; ++s) {
      const int chunk = wid * 2 + s;                 // 0..7
      const int eoff = (chunk * 64 + lane) * 8;      // element offset in tile
      const int r = eoff >> 5, c = eoff & 31;
      gload_lds16(A + (size_t)(r0 + r) * K + k0 + c, (char*)As + chunk * 1024);
      gload_lds16(W + (size_t)(c0 + r) * K + k0 + c, (char*)Ws + chunk * 1024);
    }
    __syncthreads();
    bf16x8 af[4], wf[4];
#pragma unroll
    for (int mi = 0; mi < 4; ++mi)
      af[mi] = *reinterpret_cast<const bf16x8*>(
          &As[(wr * 64 + mi * 16 + l15) * 32 + lg * 8]);
#pragma unroll
    for (int ni = 0; ni < 4; ++ni)
      wf[ni] = *reinterpret_cast<const bf16x8*>(
          &Ws[(wc * 64 + ni * 16 + l15) * 32 + lg * 8]);
#pragma unroll
    for (int mi = 0; mi < 4; ++mi)
#pragma unroll
      for (int ni = 0; ni < 4; ++ni)
        acc[mi][ni] = __builtin_amdgcn_mfma_f32_16x16x32_bf16(
            af[mi], wf[ni], acc[mi][ni], 0, 0, 0);
    __syncthreads();
  }

#pragma unroll
  for (int mi = 0; mi < 4; ++mi)
#pragma unroll
    for (int ni = 0; ni < 4; ++ni)
#pragma unroll
      for (int j = 0; j < 4; ++j) {
        const int row = r0 + wr * 64 + mi * 16 + lg * 4 + j;
        const int col = c0 + wc * 64 + ni * 16 + l15;
        const float v = acc[mi][ni][j];
        if constexpr (__is_same(OutT, float))
          C[(size_t)row * N + col] = v;
        else
          C[(size_t)row * N + col] = (bf16_t)v;
      }
}

// ---------------- RoPE + layout: qkv[4096][3072] -> Qr/Kr/Vt ----------------
// Qr[B][16][T][128], Kr[B][4][T][128], Vt[B][4][128][T]
__global__ __launch_bounds__(256) void rope_layout(
    const bf16_t* __restrict__ qkv, const float* __restrict__ fc,
    const float* __restrict__ fs, bf16_t* __restrict__ Qr,
    bf16_t* __restrict__ Kr, bf16_t* __restrict__ Vt) {
  const int n = blockIdx.x;                 // 0..4095
  const int b = n >> 11, t = n & 2047;
  const int tid = threadIdx.x;
  const bf16_t* row = qkv + (size_t)n * 3072;

  // Q: 16 heads * 64 pairs = 1024 pairs
#pragma unroll
  for (int i = 0; i < 4; ++i) {
    const int p = i * 256 + tid;
    const int h = p >> 6, j = p & 63;
    const float t0 = (float)row[h * 128 + 2 * j];
    const float t1 = (float)row[h * 128 + 2 * j + 1];
    const float c = fc[t * 64 + j], s = fs[t * 64 + j];
    const size_t dst = ((size_t)(b * 16 + h) * 2048 + t) * 128 + 2 * j;
    Qr[dst] = (bf16_t)(t0 * c - t1 * s);
    Qr[dst + 1] = (bf16_t)(t0 * s + t1 * c);
  }
  // K: 4 kv-heads * 64 pairs = 256 pairs
  {
    const int kvh = tid >> 6, j = tid & 63;
    const float t0 = (float)row[2048 + kvh * 128 + 2 * j];
    const float t1 = (float)row[2048 + kvh * 128 + 2 * j + 1];
    const float c = fc[t * 64 + j], s = fs[t * 64 + j];
    const size_t dst = ((size_t)(b * 4 + kvh) * 2048 + t) * 128 + 2 * j;
    Kr[dst] = (bf16_t)(t0 * c - t1 * s);
    Kr[dst + 1] = (bf16_t)(t0 * s + t1 * c);
  }
  // V: 512 elems, transposed store
#pragma unroll
  for (int i = 0; i < 2; ++i) {
    const int e = i * 256 + tid;
    const int kvh = e >> 7, d = e & 127;
    Vt[((size_t)(b * 4 + kvh) * 128 + d) * 2048 + t] = row[2560 + e];
  }
}

// ---------------- causal GQA flash attention ----------------
// block = 4 waves; block handles (b, h, 64 q-rows); wave owns 16 q-rows.
// KVBLK = 32.  Writes attn_out[4096][2048] bf16.
__global__ __launch_bounds__(256) void attn_fwd(
    const bf16_t* __restrict__ Qr, const bf16_t* __restrict__ Kr,
    const bf16_t* __restrict__ Vt, bf16_t* __restrict__ Oout) {
  __shared__ bf16_t Plds[4][16 * 32];
  const int lane = threadIdx.x & 63, w = threadIdx.x >> 6;
  const int l15 = lane & 15, lg = lane >> 4;
  const int q0 = blockIdx.x * 64;
  const int h = blockIdx.y, b = blockIdx.z;
  const int kv = h >> 2;                      // G = 4
  const int qb = q0 + w * 16;

  const bf16_t* Qbase = Qr + ((size_t)(b * 16 + h) * 2048 + qb) * 128;
  const bf16_t* Kbase = Kr + ((size_t)(b * 4 + kv) * 2048) * 128;
  const bf16_t* Vbase = Vt + ((size_t)(b * 4 + kv) * 128) * 2048;

  bf16x8 qf[4];
#pragma unroll
  for (int dt = 0; dt < 4; ++dt)
    qf[dt] = *reinterpret_cast<const bf16x8*>(Qbase + (size_t)l15 * 128 +
                                              dt * 32 + lg * 8);

  float m[4], lsum[4];
  f32x4 o[8];
#pragma unroll
  for (int j = 0; j < 4; ++j) { m[j] = -1e30f; lsum[j] = 0.f; }
#pragma unroll
  for (int d8 = 0; d8 < 8; ++d8)
#pragma unroll
    for (int j = 0; j < 4; ++j) o[d8][j] = 0.f;

  bf16_t* pw = &Plds[w][0];
  const int ktiles = (q0 + 64) >> 5;
  for (int kt = 0; kt < ktiles; ++kt) {
    const int k0 = kt * 32;
    f32x4 s0, s1;
#pragma unroll
    for (int j = 0; j < 4; ++j) { s0[j] = 0.f; s1[j] = 0.f; }
#pragma unroll
    for (int dt = 0; dt < 4; ++dt) {
      bf16x8 kf0 = *reinterpret_cast<const bf16x8*>(
          Kbase + (size_t)(k0 + l15) * 128 + dt * 32 + lg * 8);
      bf16x8 kf1 = *reinterpret_cast<const bf16x8*>(
          Kbase + (size_t)(k0 + 16 + l15) * 128 + dt * 32 + lg * 8);
      s0 = __builtin_amdgcn_mfma_f32_16x16x32_bf16(qf[dt], kf0, s0, 0, 0, 0);
      s1 = __builtin_amdgcn_mfma_f32_16x16x32_bf16(qf[dt], kf1, s1, 0, 0, 0);
    }
#pragma unroll
    for (int j = 0; j < 4; ++j) {
      const int q = qb + lg * 4 + j;
      float v0 = s0[j] * SCALE_QK; if (k0 + l15 > q)      v0 = -1e9f;
      float v1 = s1[j] * SCALE_QK; if (k0 + 16 + l15 > q) v1 = -1e9f;
      float tmax = fmaxf(v0, v1);
#pragma unroll
      for (int off = 1; off < 16; off <<= 1)
        tmax = fmaxf(tmax, __shfl_xor(tmax, off));
      const float mnew = fmaxf(m[j], tmax);
      const float cf = __expf(m[j] - mnew);
      const float p0 = __expf(v0 - mnew);
      const float p1 = __expf(v1 - mnew);
      float rs = p0 + p1;
#pragma unroll
      for (int off = 1; off < 16; off <<= 1) rs += __shfl_xor(rs, off);
      lsum[j] = lsum[j] * cf + rs;
      m[j] = mnew;
#pragma unroll
      for (int d8 = 0; d8 < 8; ++d8) o[d8][j] *= cf;
      pw[(lg * 4 + j) * 32 + l15] = (bf16_t)p0;
      pw[(lg * 4 + j) * 32 + 16 + l15] = (bf16_t)p1;
    }
    __syncthreads();  // drain LDS writes (all waves share the same trip count)
    bf16x8 pa = *reinterpret_cast<const bf16x8*>(pw + l15 * 32 + lg * 8);
#pragma unroll
    for (int d8 = 0; d8 < 8; ++d8) {
      bf16x8 vf = *reinterpret_cast<const bf16x8*>(
          Vbase + (size_t)(d8 * 16 + l15) * 2048 + k0 + lg * 8);
      o[d8] = __builtin_amdgcn_mfma_f32_16x16x32_bf16(pa, vf, o[d8], 0, 0, 0);
    }
  }

  float inv[4];
#pragma unroll
  for (int j = 0; j < 4; ++j) inv[j] = 1.f / lsum[j];
#pragma unroll
  for (int d8 = 0; d8 < 8; ++d8)
#pragma unroll
    for (int j = 0; j < 4; ++j) {
      const size_t n = (size_t)b * 2048 + qb + lg * 4 + j;
      Oout[n * 2048 + h * 128 + d8 * 16 + l15] = (bf16_t)(o[d8][j] * inv[j]);
    }
}

// ---------------- host launch ----------------
extern "C" void kernel_launch(void* const* d_in, const int* in_sizes, int n_in,
                              void* d_out, int out_size, void* d_ws,
                              size_t ws_size, hipStream_t stream) {
  const float* x  = (const float*)d_in[0];
  const float* wq = (const float*)d_in[1];
  const float* wk = (const float*)d_in[2];
  const float* wv = (const float*)d_in[3];
  const float* wo = (const float*)d_in[4];
  const float* fc = (const float*)d_in[5];
  const float* fs = (const float*)d_in[6];
  float* out = (float*)d_out;

  char* ws = (char*)d_ws;
  // layout (bytes)
  bf16_t* xb      = (bf16_t*)(ws + 0);             // 16,777,216  (also attn_out later)
  bf16_t* wqkv    = (bf16_t*)(ws + 16777216);      // 12,582,912
  bf16_t* wo_b    = (bf16_t*)(ws + 29360128);      //  8,388,608
  bf16_t* qkv     = (bf16_t*)(ws + 37748736);      // 25,165,824
  bf16_t* Qr      = (bf16_t*)(ws + 62914560);      // 16,777,216
  bf16_t* Kr      = (bf16_t*)(ws + 79691776);      //  4,194,304
  bf16_t* Vt      = (bf16_t*)(ws + 83886080);      //  4,194,304  -> end 88,080,384
  bf16_t* attn_o  = xb;                            // alias: xb dead after GEMM1

  const int M = 4096;  // B*T

  // 1) converts
  cvt_f32_bf16<<<2048, 256, 0, stream>>>(x, xb, (8 * 1024 * 1024) / 4 * 4 / 4);
  cvt_f32_bf16<<<1024, 256, 0, stream>>>(wq, wqkv, 4194304 / 4);
  cvt_f32_bf16<<<512, 256, 0, stream>>>(wk, wqkv + 4194304, 1048576 / 4);
  cvt_f32_bf16<<<512, 256, 0, stream>>>(wv, wqkv + 5242880, 1048576 / 4);
  cvt_f32_bf16<<<1024, 256, 0, stream>>>(wo, wo_b, 4194304 / 4);

  // 2) QKV projection: [4096,2048] x [3072,2048]^T -> [4096,3072]
  gemm_bt<bf16_t><<<dim3(3072 / 128, M / 128), 256, 0, stream>>>(
      xb, wqkv, qkv, M, 3072, 2048);

  // 3) RoPE + layout
  rope_layout<<<4096, 256, 0, stream>>>(qkv, fc, fs, Qr, Kr, Vt);

  // 4) attention
  attn_fwd<<<dim3(2048 / 64, 16, 2), 256, 0, stream>>>(Qr, Kr, Vt, attn_o);

  // 5) output projection: [4096,2048] x [2048,2048]^T -> fp32 out
  gemm_bt<float><<<dim3(2048 / 128, M / 128), 256, 0, stream>>>(
      attn_o, wo_b, out, M, 2048, 2048);
}

// Round 2
// 401.409 us; speedup vs baseline: 1.5261x; 1.5261x over previous
//
#include <hip/hip_runtime.h>
#include <hip/hip_bf16.h>

typedef __bf16 bf16_t;
typedef __bf16 bf16x8 __attribute__((ext_vector_type(8)));
typedef __bf16 bf16x4 __attribute__((ext_vector_type(4)));
typedef float f32x4 __attribute__((ext_vector_type(4)));

#define SCALE_QK 0.08838834764831845f  // 1/sqrt(128)

struct FalseC { static constexpr bool value = false; };
struct TrueC  { static constexpr bool value = true;  };

__device__ __forceinline__ void gload_lds16(const void* g, void* l) {
  __builtin_amdgcn_global_load_lds(
      (const __attribute__((address_space(1))) void*)g,
      (__attribute__((address_space(3))) void*)l, 16, 0, 0);
}

// ---------------- fp32 -> bf16 convert ----------------
__global__ __launch_bounds__(256) void cvt_f32_bf16(
    const float* __restrict__ src, bf16_t* __restrict__ dst, int n4) {
  int i = blockIdx.x * 256 + threadIdx.x;
  const int stride = gridDim.x * 256;
  for (; i < n4; i += stride) {
    f32x4 v = *reinterpret_cast<const f32x4*>(src + (size_t)i * 4);
    bf16x4 r;
    r[0] = (bf16_t)v[0]; r[1] = (bf16_t)v[1];
    r[2] = (bf16_t)v[2]; r[3] = (bf16_t)v[3];
    *reinterpret_cast<bf16x4*>(dst + (size_t)i * 4) = r;
  }
}

// ---------------- bf16 GEMM:  C[M][N] = A[M][K] * W[N][K]^T ----------------
template <typename OutT>
__global__ __launch_bounds__(256) void gemm_bt(
    const bf16_t* __restrict__ A, const bf16_t* __restrict__ W,
    OutT* __restrict__ C, int M, int N, int K) {
  __shared__ bf16_t As[128 * 32];
  __shared__ bf16_t Ws[128 * 32];
  const int tid = threadIdx.x;
  const int lane = tid & 63;
  const int wid = tid >> 6;
  const int wr = wid >> 1, wc = wid & 1;
  const int l15 = lane & 15, lg = lane >> 4;
  const int r0 = blockIdx.y * 128;
  const int c0 = blockIdx.x * 128;

  f32x4 acc[4][4];
#pragma unroll
  for (int mi = 0; mi < 4; ++mi)
#pragma unroll
    for (int ni = 0; ni < 4; ++ni)
#pragma unroll
      for (int j = 0; j < 4; ++j) acc[mi][ni][j] = 0.f;

  for (int k0 = 0; k0 < K; k0 += 32) {
#pragma unroll
    for (int s = 0; s < 2; ++s) {
      const int chunk = wid * 2 + s;
      const int eoff = (chunk * 64 + lane) * 8;
      const int r = eoff >> 5, c = eoff & 31;
      gload_lds16(A + (size_t)(r0 + r) * K + k0 + c, (char*)As + chunk * 1024);
      gload_lds16(W + (size_t)(c0 + r) * K + k0 + c, (char*)Ws + chunk * 1024);
    }
    __syncthreads();
    bf16x8 af[4], wf[4];
#pragma unroll
    for (int mi = 0; mi < 4; ++mi)
      af[mi] = *reinterpret_cast<const bf16x8*>(
          &As[(wr * 64 + mi * 16 + l15) * 32 + lg * 8]);
#pragma unroll
    for (int ni = 0; ni < 4; ++ni)
      wf[ni] = *reinterpret_cast<const bf16x8*>(
          &Ws[(wc * 64 + ni * 16 + l15) * 32 + lg * 8]);
#pragma unroll
    for (int mi = 0; mi < 4; ++mi)
#pragma unroll
      for (int ni = 0; ni < 4; ++ni)
        acc[mi][ni] = __builtin_amdgcn_mfma_f32_16x16x32_bf16(
            af[mi], wf[ni], acc[mi][ni], 0, 0, 0);
    __syncthreads();
  }

#pragma unroll
  for (int mi = 0; mi < 4; ++mi)
#pragma unroll
    for (int ni = 0; ni < 4; ++ni)
#pragma unroll
      for (int j = 0; j < 4; ++j) {
        const int row = r0 + wr * 64 + mi * 16 + lg * 4 + j;
        const int col = c0 + wc * 64 + ni * 16 + l15;
        const float v = acc[mi][ni][j];
        if constexpr (__is_same(OutT, float))
          C[(size_t)row * N + col] = v;
        else
          C[(size_t)row * N + col] = (bf16_t)v;
      }
}

// ---------------- RoPE + layout: qkv[4096][3072] -> Qr/Kr/Vt ----------------
// Qr[B][16][T][128] (pre-scaled by 1/sqrt(D)), Kr[B][4][T][128], Vt[B][4][128][T]
__global__ __launch_bounds__(256) void rope_layout(
    const bf16_t* __restrict__ qkv, const float* __restrict__ fc,
    const float* __restrict__ fs, bf16_t* __restrict__ Qr,
    bf16_t* __restrict__ Kr, bf16_t* __restrict__ Vt) {
  const int n = blockIdx.x;
  const int b = n >> 11, t = n & 2047;
  const int tid = threadIdx.x;
  const bf16_t* row = qkv + (size_t)n * 3072;

#pragma unroll
  for (int i = 0; i < 4; ++i) {
    const int p = i * 256 + tid;
    const int h = p >> 6, j = p & 63;
    const float t0 = (float)row[h * 128 + 2 * j];
    const float t1 = (float)row[h * 128 + 2 * j + 1];
    const float c = fc[t * 64 + j], s = fs[t * 64 + j];
    const size_t dst = ((size_t)(b * 16 + h) * 2048 + t) * 128 + 2 * j;
    Qr[dst] = (bf16_t)((t0 * c - t1 * s) * SCALE_QK);
    Qr[dst + 1] = (bf16_t)((t0 * s + t1 * c) * SCALE_QK);
  }
  {
    const int kvh = tid >> 6, j = tid & 63;
    const float t0 = (float)row[2048 + kvh * 128 + 2 * j];
    const float t1 = (float)row[2048 + kvh * 128 + 2 * j + 1];
    const float c = fc[t * 64 + j], s = fs[t * 64 + j];
    const size_t dst = ((size_t)(b * 4 + kvh) * 2048 + t) * 128 + 2 * j;
    Kr[dst] = (bf16_t)(t0 * c - t1 * s);
    Kr[dst + 1] = (bf16_t)(t0 * s + t1 * c);
  }
#pragma unroll
  for (int i = 0; i < 2; ++i) {
    const int e = i * 256 + tid;
    const int kvh = e >> 7, d = e & 127;
    Vt[((size_t)(b * 4 + kvh) * 128 + d) * 2048 + t] = row[2560 + e];
  }
}

// ---------------- causal GQA flash attention ----------------
// 4 waves/block, each wave owns 32 q-rows, KVBLK = 64, no inter-wave sync.
#define PLD 72
__global__ __launch_bounds__(256, 2) void attn_fwd(
    const bf16_t* __restrict__ Qr, const bf16_t* __restrict__ Kr,
    const bf16_t* __restrict__ Vt, bf16_t* __restrict__ Oout) {
  __shared__ bf16_t Plds[4][32 * PLD];
  const int lane = threadIdx.x & 63, w = threadIdx.x >> 6;
  const int l15 = lane & 15, lg = lane >> 4;
  const int qt = gridDim.x - 1 - blockIdx.x;   // heavy blocks first
  const int h = blockIdx.y, b = blockIdx.z;
  const int kv = h >> 2;
  const int qb = qt * 128 + w * 32;

  const bf16_t* Qbase = Qr + ((size_t)(b * 16 + h) * 2048 + qb) * 128;
  const bf16_t* Kbase = Kr + ((size_t)(b * 4 + kv) * 2048) * 128;
  const bf16_t* Vbase = Vt + ((size_t)(b * 4 + kv) * 128) * 2048;

  bf16x8 qf[2][4];
#pragma unroll
  for (int qm = 0; qm < 2; ++qm)
#pragma unroll
    for (int dt = 0; dt < 4; ++dt)
      qf[qm][dt] = *reinterpret_cast<const bf16x8*>(
          Qbase + (size_t)(qm * 16 + l15) * 128 + dt * 32 + lg * 8);

  float m[2][4];
  f32x4 osum[2];
  f32x4 o[2][8];
#pragma unroll
  for (int qm = 0; qm < 2; ++qm) {
#pragma unroll
    for (int j = 0; j < 4; ++j) { m[qm][j] = -1e30f; osum[qm][j] = 0.f; }
#pragma unroll
    for (int d8 = 0; d8 < 8; ++d8)
#pragma unroll
      for (int j = 0; j < 4; ++j) o[qm][d8][j] = 0.f;
  }

  bf16x8 ones;
#pragma unroll
  for (int i = 0; i < 8; ++i) ones[i] = (bf16_t)1.0f;

  bf16_t* pw = &Plds[w][0];

  auto tile = [&](int k0, auto mc) {
    constexpr bool MASKED = decltype(mc)::value;
    f32x4 s[2][4];
#pragma unroll
    for (int qm = 0; qm < 2; ++qm)
#pragma unroll
      for (int kf = 0; kf < 4; ++kf)
#pragma unroll
        for (int j = 0; j < 4; ++j) s[qm][kf][j] = 0.f;

#pragma unroll
    for (int kf = 0; kf < 4; ++kf) {
#pragma unroll
      for (int dt = 0; dt < 4; ++dt) {
        bf16x8 kfr = *reinterpret_cast<const bf16x8*>(
            Kbase + (size_t)(k0 + kf * 16 + l15) * 128 + dt * 32 + lg * 8);
        s[0][kf] = __builtin_amdgcn_mfma_f32_16x16x32_bf16(qf[0][dt], kfr,
                                                           s[0][kf], 0, 0, 0);
        s[1][kf] = __builtin_amdgcn_mfma_f32_16x16x32_bf16(qf[1][dt], kfr,
                                                           s[1][kf], 0, 0, 0);
      }
    }

#pragma unroll
    for (int qm = 0; qm < 2; ++qm)
#pragma unroll
      for (int j = 0; j < 4; ++j) {
        const int q = qb + qm * 16 + lg * 4 + j;
        float v0 = s[qm][0][j], v1 = s[qm][1][j];
        float v2 = s[qm][2][j], v3 = s[qm][3][j];
        if (MASKED) {
          if (k0 + l15 > q)      v0 = -1e30f;
          if (k0 + 16 + l15 > q) v1 = -1e30f;
          if (k0 + 32 + l15 > q) v2 = -1e30f;
          if (k0 + 48 + l15 > q) v3 = -1e30f;
        }
        float tmax = fmaxf(fmaxf(v0, v1), fmaxf(v2, v3));
#pragma unroll
        for (int off = 1; off < 16; off <<= 1)
          tmax = fmaxf(tmax, __shfl_xor(tmax, off));
        const float mnew = fmaxf(m[qm][j], tmax);
        const float cf = __expf(m[qm][j] - mnew);
        m[qm][j] = mnew;
        const float p0 = __expf(v0 - mnew), p1 = __expf(v1 - mnew);
        const float p2 = __expf(v2 - mnew), p3 = __expf(v3 - mnew);
        osum[qm][j] *= cf;
#pragma unroll
        for (int d8 = 0; d8 < 8; ++d8) o[qm][d8][j] *= cf;
        bf16_t* pr = pw + (qm * 16 + lg * 4 + j) * PLD + l15;
        pr[0]  = (bf16_t)p0;
        pr[16] = (bf16_t)p1;
        pr[32] = (bf16_t)p2;
        pr[48] = (bf16_t)p3;
      }

#pragma unroll
    for (int ks = 0; ks < 2; ++ks) {
      bf16x8 pa0 = *reinterpret_cast<const bf16x8*>(pw + (size_t)l15 * PLD +
                                                    ks * 32 + lg * 8);
      bf16x8 pa1 = *reinterpret_cast<const bf16x8*>(
          pw + (size_t)(16 + l15) * PLD + ks * 32 + lg * 8);
      osum[0] = __builtin_amdgcn_mfma_f32_16x16x32_bf16(pa0, ones, osum[0], 0, 0, 0);
      osum[1] = __builtin_amdgcn_mfma_f32_16x16x32_bf16(pa1, ones, osum[1], 0, 0, 0);
#pragma unroll
      for (int d8 = 0; d8 < 8; ++d8) {
        bf16x8 vf = *reinterpret_cast<const bf16x8*>(
            Vbase + (size_t)(d8 * 16 + l15) * 2048 + k0 + ks * 32 + lg * 8);
        o[0][d8] = __builtin_amdgcn_mfma_f32_16x16x32_bf16(pa0, vf, o[0][d8], 0, 0, 0);
        o[1][d8] = __builtin_amdgcn_mfma_f32_16x16x32_bf16(pa1, vf, o[1][d8], 0, 0, 0);
      }
    }
  };

  const int nfull = qb >> 6;
  for (int kt = 0; kt < nfull; ++kt) tile(kt * 64, FalseC{});
  tile(nfull * 64, TrueC{});

#pragma unroll
  for (int qm = 0; qm < 2; ++qm) {
    f32x4 inv;
#pragma unroll
    for (int j = 0; j < 4; ++j) inv[j] = 1.f / osum[qm][j];
#pragma unroll
    for (int d8 = 0; d8 < 8; ++d8)
#pragma unroll
      for (int j = 0; j < 4; ++j) {
        const size_t n = (size_t)b * 2048 + qb + qm * 16 + lg * 4 + j;
        Oout[n * 2048 + h * 128 + d8 * 16 + l15] = (bf16_t)(o[qm][d8][j] * inv[j]);
      }
  }
}

// ---------------- host launch ----------------
extern "C" void kernel_launch(void* const* d_in, const int* in_sizes, int n_in,
                              void* d_out, int out_size, void* d_ws,
                              size_t ws_size, hipStream_t stream) {
  const float* x  = (const float*)d_in[0];
  const float* wq = (const float*)d_in[1];
  const float* wk = (const float*)d_in[2];
  const float* wv = (const float*)d_in[3];
  const float* wo = (const float*)d_in[4];
  const float* fc = (const float*)d_in[5];
  const float* fs = (const float*)d_in[6];
  float* out = (float*)d_out;

  char* ws = (char*)d_ws;
  bf16_t* xb      = (bf16_t*)(ws + 0);
  bf16_t* wqkv    = (bf16_t*)(ws + 16777216);
  bf16_t* wo_b    = (bf16_t*)(ws + 29360128);
  bf16_t* qkv     = (bf16_t*)(ws + 37748736);
  bf16_t* Qr      = (bf16_t*)(ws + 62914560);
  bf16_t* Kr      = (bf16_t*)(ws + 79691776);
  bf16_t* Vt      = (bf16_t*)(ws + 83886080);
  bf16_t* attn_o  = xb;

  const int M = 4096;

  cvt_f32_bf16<<<2048, 256, 0, stream>>>(x, xb, 2097152);
  cvt_f32_bf16<<<1024, 256, 0, stream>>>(wq, wqkv, 1048576);
  cvt_f32_bf16<<<512, 256, 0, stream>>>(wk, wqkv + 4194304, 262144);
  cvt_f32_bf16<<<512, 256, 0, stream>>>(wv, wqkv + 5242880, 262144);
  cvt_f32_bf16<<<1024, 256, 0, stream>>>(wo, wo_b, 1048576);

  gemm_bt<bf16_t><<<dim3(3072 / 128, M / 128), 256, 0, stream>>>(
      xb, wqkv, qkv, M, 3072, 2048);

  rope_layout<<<4096, 256, 0, stream>>>(qkv, fc, fs, Qr, Kr, Vt);

  attn_fwd<<<dim3(2048 / 128, 16, 2), 256, 0, stream>>>(Qr, Kr, Vt, attn_o);

  gemm_bt<float><<<dim3(2048 / 128, M / 128), 256, 0, stream>>>(
      attn_o, wo_b, out, M, 2048, 2048);
}